// Round 15
// baseline (1298.422 us; speedup 1.0000x reference)
//
#include <hip/hip_runtime.h>

// ---------------------------------------------------------------------------
// M3GNet forward. N=8000, E=200000, A=400000, NG=100, FD=128.
// R15 = R14 (verified 1286us) + k_edge register diet targeting occupancy:
//   (1) ein[16] preload removed -> ePq loaded in GEMM1 epilogue (coalesced,
//       L2-warm; TLP hides it -- R13 lesson: don't software-prefetch here).
//   (2) er kept packed bf16 (er2[16], 16 VGPRs) instead of f32x4[8] (32);
//       e is bf16-rounded at transpose/store anyway.
// Goal: ~32 fewer live VGPRs across Phase 0 -> 5 waves/SIMD (Occ 38->47%).
// ---------------------------------------------------------------------------

typedef short short8 __attribute__((ext_vector_type(8)));
typedef float f32x4v __attribute__((ext_vector_type(4)));

__device__ __forceinline__ float sigmoidf_(float x) { return 1.0f / (1.0f + __expf(-x)); }
__device__ __forceinline__ float swishf_(float x) { return x * sigmoidf_(x); }

__device__ __forceinline__ unsigned short f2bf(float x) {
    unsigned int u = __float_as_uint(x);
    unsigned int r = (u + 0x7FFFu + ((u >> 16) & 1u)) >> 16;
    return (unsigned short)r;
}
__device__ __forceinline__ float bf2f(unsigned short u) {
    return __uint_as_float(((unsigned int)u) << 16);
}
__device__ __forceinline__ float blo(unsigned int u) { return __uint_as_float(u << 16); }
__device__ __forceinline__ float bhi(unsigned int u) { return __uint_as_float(u & 0xffff0000u); }
__device__ __forceinline__ unsigned int pk2(float a, float b) {
    return (unsigned int)f2bf(a) | ((unsigned int)f2bf(b) << 16);
}
__device__ __forceinline__ unsigned int addbf2(unsigned int a, unsigned int b) {
    return pk2(blo(a) + blo(b), bhi(a) + bhi(b));
}

__device__ __forceinline__ f32x4v mfma_bf16(short8 a, short8 b, f32x4v c) {
    return __builtin_amdgcn_mfma_f32_16x16x32_bf16(a, b, c, 0, 0, 0);
}

__device__ __forceinline__ float4 f4add(float4 a, float4 b) {
    return make_float4(a.x + b.x, a.y + b.y, a.z + b.z, a.w + b.w);
}
__device__ __forceinline__ float4 f4swish(float4 a) {
    return make_float4(swishf_(a.x), swishf_(a.y), swishf_(a.z), swishf_(a.w));
}
__device__ __forceinline__ float getc(const float4& v, int i) {
    return i == 0 ? v.x : (i == 1 ? v.y : (i == 2 ? v.z : v.w));
}

#define FMA4(J, A) \
    acc[J].x = fmaf(A, bv.x, acc[J].x); acc[J].y = fmaf(A, bv.y, acc[J].y); \
    acc[J].z = fmaf(A, bv.z, acc[J].z); acc[J].w = fmaf(A, bv.w, acc[J].w)

template <int S>
__device__ __forceinline__ void gemm32f(const float* As, const float* __restrict__ B,
                                        int tm, int f0, float4 acc[4]) {
#pragma unroll 4
    for (int k = 0; k < 128; ++k) {
        const float4 a0 = *(const float4*)(As + k * S + (tm << 2));
        const float4 bv = *(const float4*)(B + (k << 7) + f0);
        FMA4(0, a0.x); FMA4(1, a0.y); FMA4(2, a0.z); FMA4(3, a0.w);
    }
}

// Phase-0 projection: m0/m1 = dot(ang16, Wang cols for this lane's 2 features)
#define ANG_PROJ(AP, M0, M1)                                                     \
    {                                                                            \
        const float4 A0 = (AP)[0], A1 = (AP)[1], A2 = (AP)[2], A3 = (AP)[3];     \
        float m0, m1;                                                            \
        m0 = A0.x * wc[0].x;  m1 = A0.x * wc[0].y;                               \
        m0 = fmaf(A0.y, wc[1].x, m0);  m1 = fmaf(A0.y, wc[1].y, m1);             \
        m0 = fmaf(A0.z, wc[2].x, m0);  m1 = fmaf(A0.z, wc[2].y, m1);             \
        m0 = fmaf(A0.w, wc[3].x, m0);  m1 = fmaf(A0.w, wc[3].y, m1);             \
        m0 = fmaf(A1.x, wc[4].x, m0);  m1 = fmaf(A1.x, wc[4].y, m1);             \
        m0 = fmaf(A1.y, wc[5].x, m0);  m1 = fmaf(A1.y, wc[5].y, m1);             \
        m0 = fmaf(A1.z, wc[6].x, m0);  m1 = fmaf(A1.z, wc[6].y, m1);             \
        m0 = fmaf(A1.w, wc[7].x, m0);  m1 = fmaf(A1.w, wc[7].y, m1);             \
        m0 = fmaf(A2.x, wc[8].x, m0);  m1 = fmaf(A2.x, wc[8].y, m1);             \
        m0 = fmaf(A2.y, wc[9].x, m0);  m1 = fmaf(A2.y, wc[9].y, m1);             \
        m0 = fmaf(A2.z, wc[10].x, m0); m1 = fmaf(A2.z, wc[10].y, m1);            \
        m0 = fmaf(A2.w, wc[11].x, m0); m1 = fmaf(A2.w, wc[11].y, m1);            \
        m0 = fmaf(A3.x, wc[12].x, m0); m1 = fmaf(A3.x, wc[12].y, m1);            \
        m0 = fmaf(A3.y, wc[13].x, m0); m1 = fmaf(A3.y, wc[13].y, m1);            \
        m0 = fmaf(A3.z, wc[14].x, m0); m1 = fmaf(A3.z, wc[14].y, m1);            \
        m0 = fmaf(A3.w, wc[15].x, m0); m1 = fmaf(A3.w, wc[15].y, m1);            \
        (M0) = m0; (M1) = m1;                                                    \
    }

// ---------------------------------------------------------------------------
__global__ void k_offsets(const int* __restrict__ tnb, const int* __restrict__ tna,
                          int NG, int* __restrict__ boff, int* __restrict__ acum) {
    if (threadIdx.x == 0 && blockIdx.x == 0) {
        int ab = 0, aa = 0;
        for (int g = 0; g < NG; ++g) {
            boff[g] = ab;
            ab += tnb[g];
            aa += tna[g];
            acum[g] = aa;
        }
    }
}

__global__ void k_angle_setup(const int* __restrict__ tb, const float* __restrict__ rnorm,
                              const float* __restrict__ cosang, const int* __restrict__ ei,
                              int E, int A, int NG,
                              const int* __restrict__ boff, const int* __restrict__ acum,
                              float* __restrict__ ang,
                              int* __restrict__ kat, int* __restrict__ iij,
                              int* __restrict__ cnt) {
    const int a = blockIdx.x * 256 + threadIdx.x;
    if (a >= A) return;
    int lo = 0, hi = NG - 1;
    while (lo < hi) {
        const int mid = (lo + hi) >> 1;
        if (a < acum[mid]) hi = mid; else lo = mid + 1;
    }
    const int off = boff[lo];
    iij[a] = tb[2 * a] + off;
    kat[a] = ei[(size_t)E + tb[2 * a + 1] + off];
    atomicAdd(&cnt[tb[2 * a] + off], 1);

    const float r = rnorm[a], c = cosang[a];
    const float rinv = 1.0f / r;
    const float x = r * 0.25f;
    const float fc = 1.0f + x * x * x * (-10.0f + x * (15.0f - 6.0f * x));
    const float fc2 = fc * fc;
    const float p2 = 1.5f * c * c - 0.5f;
    const float p3 = 2.5f * c * c * c - 1.5f * c;
    float4* ap = (float4*)(ang + (size_t)a * 16);
#pragma unroll
    for (int n = 0; n < 4; ++n) {
        const float rad = __sinf(r * (float)(n + 1) * 0.7853981633974483f) * rinv * fc2;
        ap[n] = make_float4(rad, rad * c, rad * p2, rad * p3);
    }
}

__global__ void k_scan1(const int* __restrict__ cnt, int* __restrict__ start,
                        int* __restrict__ bsum, int n) {
    __shared__ int sh[256];
    const int t = threadIdx.x;
    const int base = blockIdx.x * 2048 + t * 8;
    int v[8], s = 0;
#pragma unroll
    for (int i = 0; i < 8; ++i) { v[i] = (base + i < n) ? cnt[base + i] : 0; s += v[i]; }
    sh[t] = s;
    __syncthreads();
    for (int off = 1; off < 256; off <<= 1) {
        int x = (t >= off) ? sh[t - off] : 0;
        __syncthreads();
        sh[t] += x;
        __syncthreads();
    }
    if (t == 255) bsum[blockIdx.x] = sh[255];
    int run = sh[t] - s;
#pragma unroll
    for (int i = 0; i < 8; ++i) { if (base + i < n) start[base + i] = run; run += v[i]; }
}

__global__ void k_scan2(int* __restrict__ bsum, int nb) {
    __shared__ int sh[256];
    const int t = threadIdx.x;
    int v = (t < nb) ? bsum[t] : 0;
    sh[t] = v;
    __syncthreads();
    for (int off = 1; off < 256; off <<= 1) {
        int x = (t >= off) ? sh[t - off] : 0;
        __syncthreads();
        sh[t] += x;
        __syncthreads();
    }
    if (t < nb) bsum[t] = sh[t] - v;
}

__global__ void k_scan3(int* __restrict__ start, const int* __restrict__ bsum, int n) {
    const int i = blockIdx.x * 256 + threadIdx.x;
    if (i < n) start[i] += bsum[i >> 11];
}

__global__ void k_scatter(const float* __restrict__ ang,
                          const int* __restrict__ kat, const int* __restrict__ iij,
                          const int* __restrict__ start, int* __restrict__ fill,
                          float* __restrict__ angS, int* __restrict__ katS, int A) {
    const int a = blockIdx.x * 256 + threadIdx.x;
    if (a >= A) return;
    const int ij = iij[a];
    const int pos = start[ij] + atomicAdd(&fill[ij], 1);
    const float4* src = (const float4*)(ang + (size_t)a * 16);
    float4* dst = (float4*)(angS + (size_t)pos * 16);
#pragma unroll
    for (int j = 0; j < 4; ++j) dst[j] = src[j];
    katS[pos] = kat[a];
}

__global__ void k_hist_recv(const int* __restrict__ ei, int E, int* __restrict__ cntR) {
    const int e = blockIdx.x * 256 + threadIdx.x;
    if (e < E) atomicAdd(&cntR[ei[(size_t)E + e]], 1);
}

__global__ void k_scatter_recv(const int* __restrict__ ei, int E,
                               const int* __restrict__ startR, int* __restrict__ fillR,
                               int* __restrict__ epos) {
    const int e = blockIdx.x * 256 + threadIdx.x;
    if (e < E) {
        const int r = ei[(size_t)E + e];
        epos[e] = startR[r] + atomicAdd(&fillR[r], 1);
    }
}

// pack 32 weight matrices into MFMA B-frag layout (bf16).
// mat = b*8 + {0:Wg, 1:We1a, 2:We1b, 3:Wa1a, 4:Wa1b, 5:Wtb, 6:We1c, 7:Wa1c}
__global__ void k_pack(const float* __restrict__ Wg, const float* __restrict__ Wtb,
                       const float* __restrict__ We1, const float* __restrict__ Wa1,
                       unsigned short* __restrict__ Bpk) {
    const int gid = blockIdx.x * 256 + threadIdx.x;  // 0..65535
    const int mat = gid >> 11;
    const int t2 = gid & 2047;
    const int b = mat >> 3, which = mat & 7;
    const float* W;
    switch (which) {
        case 0: W = Wg + (size_t)b * 16384; break;
        case 1: W = We1 + (size_t)b * 49152; break;
        case 2: W = We1 + (size_t)b * 49152 + 16384; break;
        case 3: W = Wa1 + (size_t)b * 49152; break;
        case 4: W = Wa1 + (size_t)b * 49152 + 16384; break;
        case 5: W = Wtb + (size_t)b * 16384; break;
        case 6: W = We1 + (size_t)b * 49152 + 32768; break;
        default: W = Wa1 + (size_t)b * 49152 + 32768; break;
    }
    const int kc = t2 >> 9, nt = (t2 >> 6) & 7, lane = t2 & 63;
    const int q = lane >> 4, cc = lane & 15;
    const int col = nt * 16 + cc;
    union { unsigned short us[8]; uint4 v; } pk;
#pragma unroll
    for (int j = 0; j < 8; ++j)
        pk.us[j] = f2bf(W[(size_t)(kc * 32 + q * 8 + j) * 128 + col]);
    *(uint4*)(Bpk + (size_t)mat * 16384 + (size_t)((kc * 8 + nt) * 64 + lane) * 8) = pk.v;
}

// e init, slot-major layout: ePq[(strip*16 + s)*64 + lane], s = nt*2 + half.
__global__ void k_edge_init(const float* __restrict__ dist, const float* __restrict__ Wenc,
                            const float* __restrict__ benc, unsigned int* __restrict__ ePq,
                            float* __restrict__ ef0) {
    __shared__ float sarr[16][5];
    const int s = blockIdx.x, t = threadIdx.x;
    if (t < 16) {
        const float r = dist[s * 16 + t];
        const float rinv = 1.0f / r;
#pragma unroll
        for (int n = 0; n < 5; ++n) {
            const float v = 0.6324555320336759f * __sinf(r * (float)(n + 1) * 0.6283185307179586f) * rinv;
            sarr[t][n] = v;
            ef0[(size_t)(s * 16 + t) * 5 + n] = v;
        }
    }
    __syncthreads();
    const int lane = t >> 3, nt = t & 7;
    const int q = lane >> 4;
    const int f = nt * 16 + (lane & 15);
    float wv[5];
#pragma unroll
    for (int n = 0; n < 5; ++n) wv[n] = Wenc[n * 128 + f];
    const float bz = benc[f];
    float o[4];
#pragma unroll
    for (int r = 0; r < 4; ++r) {
        const int m = q * 4 + r;
        float acc = bz;
#pragma unroll
        for (int n = 0; n < 5; ++n) acc = fmaf(sarr[m][n], wv[n], acc);
        o[r] = swishf_(acc);
    }
    unsigned int* epB = ePq + (size_t)s * 1024;
    epB[(nt * 2) * 64 + lane] = pk2(o[0], o[1]);
    epB[(nt * 2 + 1) * 64 + lane] = pk2(o[2], o[3]);
}

// atom init: v fp32 + vq bf16-packed (lane j holds features 2j,2j+1)
__global__ void k_atom_init(const int* __restrict__ an, const float* __restrict__ emb,
                            float* __restrict__ v, unsigned int* __restrict__ vq, int N) {
    const size_t gid = (size_t)blockIdx.x * 256 + threadIdx.x;
    if (gid >= (size_t)N * 64) return;
    const int a = (int)(gid >> 6), j = (int)(gid & 63);
    const float2 e = *(const float2*)(emb + (size_t)an[a] * 128 + 2 * j);
    *(float2*)(v + (size_t)a * 128 + 2 * j) = e;
    vq[gid] = pk2(e.x, e.y);
}

// ---------------------------------------------------------------------------
// MFMA per-atom GEMMs: 64 atoms/block, wave w owns atoms 16w..16w+15.
__global__ void __launch_bounds__(256, 4) k_atom_pre(
    const unsigned int* __restrict__ vq,
    const unsigned short* __restrict__ Bpk5, const float* __restrict__ bg,
    unsigned int* __restrict__ Gq, unsigned int* __restrict__ Pe1q,
    unsigned int* __restrict__ Pe2q,
    unsigned int* __restrict__ Pa1q, unsigned int* __restrict__ Pa2q) {
    __shared__ __align__(16) unsigned short At[64 * 136];
    unsigned int* At32 = (unsigned int*)At;
    const int t = threadIdx.x;
    const int w = t >> 6, l = t & 63;
    const int q = l >> 4, c = l & 15;
    const int g = blockIdx.y;
    const int abase = blockIdx.x * 64 + 16 * w;

    const unsigned short* vh = (const unsigned short*)vq;
    short8 af[4];
#pragma unroll
    for (int kc = 0; kc < 4; ++kc)
        af[kc] = *(const short8*)(vh + (size_t)(abase + c) * 128 + kc * 32 + q * 8);

    const short8* Bp = (const short8*)(Bpk5 + (size_t)g * 16384);
    const f32x4v zz = {0.0f, 0.0f, 0.0f, 0.0f};
    f32x4v acc[8];
#pragma unroll
    for (int nt = 0; nt < 8; ++nt) acc[nt] = zz;
#pragma unroll
    for (int nt = 0; nt < 8; ++nt)
#pragma unroll
        for (int kc = 0; kc < 4; ++kc)
            acc[nt] = mfma_bf16(af[kc], Bp[(kc * 8 + nt) * 64 + l], acc[nt]);

    unsigned int* OUT = (g == 0) ? Gq : (g == 1) ? Pe1q : (g == 2) ? Pe2q
                      : (g == 3) ? Pa1q : Pa2q;
#pragma unroll
    for (int nt = 0; nt < 8; ++nt) {
        const int fo = nt * 16 + c;
        if (g == 0) {
            const float bz = bg[fo];
#pragma unroll
            for (int r = 0; r < 4; ++r)
                At[(16 * w + q * 4 + r) * 136 + fo] = f2bf(sigmoidf_(acc[nt][r] + bz));
        } else {
#pragma unroll
            for (int r = 0; r < 4; ++r)
                At[(16 * w + q * 4 + r) * 136 + fo] = f2bf(acc[nt][r]);
        }
    }
#pragma unroll
    for (int j = 0; j < 16; ++j)
        OUT[(size_t)(abase + j) * 64 + l] = At32[(16 * w + j) * 68 + l];
}

// ---------------------------------------------------------------------------
// Fused per-edge kernel: Phase 0 (flat CSR loop) + 3 MFMA GEMMs.
// er kept packed bf16 (er2[16]); ePq loaded in GEMM1 epilogue (not preloaded).
__global__ void __launch_bounds__(256, 4) k_edge(
    const float* __restrict__ angS, const int* __restrict__ katS,
    const int* __restrict__ startA, const int* __restrict__ cntA,
    const unsigned int* __restrict__ Gq, const float* __restrict__ Wang,
    const float* __restrict__ ef0g,
    unsigned int* __restrict__ ePq, const int* __restrict__ ei, int E,
    const unsigned int* __restrict__ Pe1q, const unsigned int* __restrict__ Pe2q,
    const unsigned int* __restrict__ Pa1q, const unsigned int* __restrict__ Pa2q,
    const int* __restrict__ epos,
    const unsigned short* __restrict__ Bpk3,
    const float* __restrict__ btb, const float* __restrict__ be1,
    const float* __restrict__ We0, const float* __restrict__ ba1,
    const float* __restrict__ Wa0, unsigned int* __restrict__ mPq) {
    __shared__ __align__(16) unsigned short At[64 * 136];
    __shared__ __align__(16) unsigned short sPh[64 * 136];
    __shared__ float sef0[320];
    __shared__ int sA0[64], sAn[64];
    unsigned int* At32 = (unsigned int*)At;
    unsigned int* sP32 = (unsigned int*)sPh;

    const int t = threadIdx.x;
    const int w = t >> 6, l = t & 63;
    const int q = l >> 4, c = l & 15;
    const int g4 = l >> 4, l16 = l & 15;
    const size_t base = (size_t)blockIdx.x * 64;
    const int wbase = (int)base + 16 * w;

    for (int i = t; i < 320; i += 256) sef0[i] = ef0g[base * 5 + i];
    if (l < 16) {
        sA0[16 * w + l] = startA[wbase + l];
        sAn[16 * w + l] = cntA[wbase + l];
    }

    int esr[4], rcr[4];
#pragma unroll
    for (int i = 0; i < 4; ++i) {
        const int j = i * 4 + g4;
        esr[i] = ei[wbase + j];
        rcr[i] = ei[(size_t)E + wbase + j];
    }

#define STAGE_SP(P1, P2)                                                         \
    _Pragma("unroll") for (int i = 0; i < 4; ++i) {                              \
        const int j = i * 4 + g4;                                                \
        const uint4 u1 = *(const uint4*)((P1) + (size_t)esr[i] * 64 + l16 * 4);  \
        const uint4 u2 = *(const uint4*)((P2) + (size_t)rcr[i] * 64 + l16 * 4);  \
        uint4 o;                                                                 \
        o.x = addbf2(u1.x, u2.x); o.y = addbf2(u1.y, u2.y);                      \
        o.z = addbf2(u1.z, u2.z); o.w = addbf2(u1.w, u2.w);                      \
        *(uint4*)(sP32 + (16 * w + j) * 68 + l16 * 4) = o;                       \
    }

    // stage Pe sums into LDS ahead of Phase 0 (consumed after the barrier)
    STAGE_SP(Pe1q, Pe2q)
    unsigned int* epB = ePq + (size_t)(blockIdx.x * 4 + w) * 1024;  // slot-major

    // ---- Phase 0: flat loop over this wave's contiguous angle range.
    {
        float2 wc[16];
#pragma unroll
        for (int k = 0; k < 16; ++k) wc[k] = *(const float2*)(Wang + k * 128 + 2 * l);

        int j = 0;
        const int aBeg = __builtin_amdgcn_readfirstlane(sA0[16 * w]);
        const int aEnd = __builtin_amdgcn_readfirstlane(sA0[16 * w + 15] + sAn[16 * w + 15]);
        int nextB = __builtin_amdgcn_readfirstlane(sA0[16 * w] + sAn[16 * w]);
        float aa0 = 0.0f, aa1 = 0.0f;

#define FLUSH_TO(AIDX)                                                           \
        while ((AIDX) >= nextB && j < 15) {                                      \
            At32[(16 * w + j) * 68 + l] = pk2(aa0, aa1);                         \
            aa0 = 0.0f; aa1 = 0.0f;                                              \
            ++j;                                                                 \
            nextB = __builtin_amdgcn_readfirstlane(sA0[16 * w + j] + sAn[16 * w + j]); \
        }

        int a = aBeg;
        for (; a + 1 < aEnd; a += 2) {
            const int ka0 = __builtin_amdgcn_readfirstlane(katS[a]);
            const int ka1 = __builtin_amdgcn_readfirstlane(katS[a + 1]);
            const unsigned int gv0 = Gq[(size_t)ka0 * 64 + l];
            const unsigned int gv1 = Gq[(size_t)ka1 * 64 + l];
            const float4* ap0 = (const float4*)(angS + (size_t)a * 16);
            const float4* ap1 = (const float4*)(angS + (size_t)(a + 1) * 16);
            float m0a, m1a, m0b, m1b;
            ANG_PROJ(ap0, m0a, m1a)
            ANG_PROJ(ap1, m0b, m1b)
            FLUSH_TO(a)
            aa0 = fmaf(m0a, blo(gv0), aa0);
            aa1 = fmaf(m1a, bhi(gv0), aa1);
            FLUSH_TO(a + 1)
            aa0 = fmaf(m0b, blo(gv1), aa0);
            aa1 = fmaf(m1b, bhi(gv1), aa1);
        }
        if (a < aEnd) {
            const int ka0 = __builtin_amdgcn_readfirstlane(katS[a]);
            const unsigned int gv0 = Gq[(size_t)ka0 * 64 + l];
            const float4* ap0 = (const float4*)(angS + (size_t)a * 16);
            float m0a, m1a;
            ANG_PROJ(ap0, m0a, m1a)
            FLUSH_TO(a)
            aa0 = fmaf(m0a, blo(gv0), aa0);
            aa1 = fmaf(m1a, bhi(gv0), aa1);
        }
        At32[(16 * w + j) * 68 + l] = pk2(aa0, aa1);
        for (int jj = j + 1; jj < 16; ++jj) At32[(16 * w + jj) * 68 + l] = 0u;
#undef FLUSH_TO
    }
    __syncthreads();   // the only cross-wave barrier

    const short8* Bp1 = (const short8*)Bpk3;
    const short8* Bp2 = Bp1 + 2048;
    const short8* Bp3 = Bp2 + 2048;
    const f32x4v zz = {0.0f, 0.0f, 0.0f, 0.0f};

    short8 af[4];
#define LOAD_AF                                                                  \
    _Pragma("unroll") for (int kc = 0; kc < 4; ++kc)                             \
        af[kc] = *(const short8*)(At + (16 * w + c) * 136 + kc * 32 + q * 8);
// transpose from packed er2: row=edge (q*4+r), col=feature (nt*16+c)
#define TRANSPOSE_ER2                                                            \
    _Pragma("unroll") for (int nt = 0; nt < 8; ++nt) {                           \
        At[(16 * w + q * 4 + 0) * 136 + nt * 16 + c] = (unsigned short)er2[2 * nt];        \
        At[(16 * w + q * 4 + 1) * 136 + nt * 16 + c] = (unsigned short)(er2[2 * nt] >> 16);\
        At[(16 * w + q * 4 + 2) * 136 + nt * 16 + c] = (unsigned short)er2[2 * nt + 1];    \
        At[(16 * w + q * 4 + 3) * 136 + nt * 16 + c] = (unsigned short)(er2[2 * nt + 1] >> 16);\
    }

    // ---- GEMM1: agg @ Wtb; e += swish(. + btb)   (er kept packed bf16)
    LOAD_AF
    f32x4v acc[8];
#pragma unroll
    for (int nt = 0; nt < 8; ++nt) acc[nt] = zz;
#pragma unroll
    for (int nt = 0; nt < 8; ++nt)
#pragma unroll
        for (int kc = 0; kc < 4; ++kc)
            acc[nt] = mfma_bf16(af[kc], Bp1[(kc * 8 + nt) * 64 + l], acc[nt]);

    unsigned int er2[16];
#pragma unroll
    for (int nt = 0; nt < 8; ++nt) {
        const unsigned int e0 = epB[(2 * nt) * 64 + l];       // coalesced, L2-warm
        const unsigned int e1 = epB[(2 * nt + 1) * 64 + l];
        const float bt = btb[nt * 16 + c];
        er2[2 * nt] = pk2(blo(e0) + swishf_(acc[nt][0] + bt),
                          bhi(e0) + swishf_(acc[nt][1] + bt));
        er2[2 * nt + 1] = pk2(blo(e1) + swishf_(acc[nt][2] + bt),
                              bhi(e1) + swishf_(acc[nt][3] + bt));
    }
    TRANSPOSE_ER2   // wave-private slab: no barrier needed

    float efs[4][5];
#pragma unroll
    for (int r = 0; r < 4; ++r)
#pragma unroll
        for (int n = 0; n < 5; ++n) efs[r][n] = sef0[(16 * w + q * 4 + r) * 5 + n];

    // ---- GEMM2: e @ We1[256:384]; e += swish(. + be1 + Psum) * (ef0@We0)
    LOAD_AF
#pragma unroll
    for (int nt = 0; nt < 8; ++nt) acc[nt] = zz;
#pragma unroll
    for (int nt = 0; nt < 8; ++nt)
#pragma unroll
        for (int kc = 0; kc < 4; ++kc)
            acc[nt] = mfma_bf16(af[kc], Bp2[(kc * 8 + nt) * 64 + l], acc[nt]);
#pragma unroll
    for (int nt = 0; nt < 8; ++nt) {
        const int fo = nt * 16 + c;
        const float bt = be1[fo];
        const float w0 = We0[fo], w1 = We0[128 + fo], w2 = We0[256 + fo],
                    w3 = We0[384 + fo], w4 = We0[512 + fo];
        float vv[4];
#pragma unroll
        for (int r = 0; r < 4; ++r) {
            const float p12 = bf2f(sPh[(16 * w + q * 4 + r) * 136 + fo]);
            const float x = acc[nt][r] + bt + p12;
            float sc = efs[r][0] * w0;
            sc = fmaf(efs[r][1], w1, sc);
            sc = fmaf(efs[r][2], w2, sc);
            sc = fmaf(efs[r][3], w3, sc);
            sc = fmaf(efs[r][4], w4, sc);
            const unsigned int eold = er2[2 * nt + (r >> 1)];
            const float eb = (r & 1) ? bhi(eold) : blo(eold);
            vv[r] = eb + swishf_(x) * sc;
        }
        er2[2 * nt] = pk2(vv[0], vv[1]);
        er2[2 * nt + 1] = pk2(vv[2], vv[3]);
        epB[(2 * nt) * 64 + l] = er2[2 * nt];          // coalesced
        epB[(2 * nt + 1) * 64 + l] = er2[2 * nt + 1];  // coalesced
    }
    STAGE_SP(Pa1q, Pa2q)
    TRANSPOSE_ER2

    // ---- GEMM3: e @ Wa1[256:384]; m -> At (bf16) -> mPq at recv-sorted slots
    LOAD_AF
#pragma unroll
    for (int nt = 0; nt < 8; ++nt) acc[nt] = zz;
#pragma unroll
    for (int nt = 0; nt < 8; ++nt)
#pragma unroll
        for (int kc = 0; kc < 4; ++kc)
            acc[nt] = mfma_bf16(af[kc], Bp3[(kc * 8 + nt) * 64 + l], acc[nt]);
#pragma unroll
    for (int nt = 0; nt < 8; ++nt) {
        const int fo = nt * 16 + c;
        const float bt = ba1[fo];
        const float w0 = Wa0[fo], w1 = Wa0[128 + fo], w2 = Wa0[256 + fo],
                    w3 = Wa0[384 + fo], w4 = Wa0[512 + fo];
#pragma unroll
        for (int r = 0; r < 4; ++r) {
            const float p12 = bf2f(sPh[(16 * w + q * 4 + r) * 136 + fo]);
            const float x = acc[nt][r] + bt + p12;
            float sc = efs[r][0] * w0;
            sc = fmaf(efs[r][1], w1, sc);
            sc = fmaf(efs[r][2], w2, sc);
            sc = fmaf(efs[r][3], w3, sc);
            sc = fmaf(efs[r][4], w4, sc);
            At[(16 * w + q * 4 + r) * 136 + fo] = f2bf(swishf_(x) * sc);
        }
    }
#pragma unroll
    for (int j = 0; j < 16; ++j) {
        const int ep = epos[wbase + j];
        mPq[(size_t)ep * 64 + l] = At32[(16 * w + j) * 68 + l];  // 256B full-line row
    }
#undef LOAD_AF
#undef TRANSPOSE_ER2
#undef STAGE_SP
}

// dv aggregation (streaming reads: mPq is recv-sorted) fused with v update + vq
__global__ void k_dvagg(const unsigned int* __restrict__ mPq,
                        const int* __restrict__ startR, const int* __restrict__ cntR,
                        float* __restrict__ v, unsigned int* __restrict__ vq, int N) {
    const int a = blockIdx.x * 4 + (threadIdx.x >> 6);
    if (a >= N) return;
    const int l = threadIdx.x & 63;
    const int s0 = startR[a], n = cntR[a];
    float a0 = 0.0f, a1 = 0.0f;
    for (int i = 0; i < n; ++i) {
        const unsigned int u = mPq[(size_t)(s0 + i) * 64 + l];
        a0 += blo(u);
        a1 += bhi(u);
    }
    const float v0 = v[(size_t)a * 128 + 2 * l] + a0;
    const float v1 = v[(size_t)a * 128 + 2 * l + 1] + a1;
    v[(size_t)a * 128 + 2 * l] = v0;
    v[(size_t)a * 128 + 2 * l + 1] = v1;
    vq[(size_t)a * 64 + l] = pk2(v0, v1);
}

__global__ void k_readout(const float* __restrict__ v,
                          const float* __restrict__ W1, const float* __restrict__ b1,
                          const float* __restrict__ W2, const float* __restrict__ b2,
                          const float* __restrict__ W3, const float* __restrict__ b3,
                          float* __restrict__ out) {
    __shared__ float At[128 * 36];
    const int t = threadIdx.x;
    const int tn = t & 31, tm = t >> 5;
    const int f0 = tn << 2;
    const size_t base = (size_t)blockIdx.x * 32;
    {
        const int m = t & 31, cb = t >> 5;
        const float4* src = (const float4*)(v + (base + m) * 128);
#pragma unroll
        for (int i = 0; i < 4; ++i) {
            const int c = cb + (i << 3);
            const float4 ld = src[c];
            float* dst = At + (c << 2) * 32 + m;
            dst[0] = ld.x; dst[32] = ld.y; dst[64] = ld.z; dst[96] = ld.w;
        }
    }
    __syncthreads();
    float4 acc[4] = {};
    gemm32f<32>(At, W1, tm, f0, acc);
    {
        const float4 bv1 = *(const float4*)(b1 + f0);
#pragma unroll
        for (int j = 0; j < 4; ++j) acc[j] = f4swish(f4add(acc[j], bv1));
    }
    __syncthreads();
#pragma unroll
    for (int i = 0; i < 4; ++i) {
        float4 w0;
        w0.x = getc(acc[0], i); w0.y = getc(acc[1], i); w0.z = getc(acc[2], i); w0.w = getc(acc[3], i);
        *(float4*)(At + (f0 + i) * 36 + (tm << 2)) = w0;
    }
    __syncthreads();
    float4 acc2[4] = {};
    gemm32f<36>(At, W2, tm, f0, acc2);
    const float4 bv2 = *(const float4*)(b2 + f0);
    const float4 w3v = *(const float4*)(W3 + f0);
#pragma unroll
    for (int j = 0; j < 4; ++j) {
        const float4 h = f4swish(f4add(acc2[j], bv2));
        float p = h.x * w3v.x + h.y * w3v.y + h.z * w3v.z + h.w * w3v.w;
        p += __shfl_xor(p, 16);
        p += __shfl_xor(p, 8);
        p += __shfl_xor(p, 4);
        p += __shfl_xor(p, 2);
        p += __shfl_xor(p, 1);
        if (tn == 0) out[base + (tm << 2) + j] = p + b3[0];
    }
}

// ---------------------------------------------------------------------------
extern "C" void kernel_launch(void* const* d_in, const int* in_sizes, int n_in,
                              void* d_out, int out_size, void* d_ws, size_t ws_size,
                              hipStream_t stream) {
    const int N = in_sizes[0];
    const int E = in_sizes[2];
    const int A = in_sizes[4];
    const int NG = in_sizes[6];

    const int* an = (const int*)d_in[0];
    const int* ei = (const int*)d_in[1];
    const float* dist = (const float*)d_in[2];
    const int* tb = (const int*)d_in[3];
    const float* rnorm = (const float*)d_in[4];
    const float* cosang = (const float*)d_in[5];
    const int* tnb = (const int*)d_in[6];
    const int* tna = (const int*)d_in[7];
    const float* emb = (const float*)d_in[8];
    const float* Wenc = (const float*)d_in[9];
    const float* benc = (const float*)d_in[10];
    const float* Wang = (const float*)d_in[11];
    const float* Wg = (const float*)d_in[12];
    const float* bg = (const float*)d_in[13];
    const float* Wtb = (const float*)d_in[14];
    const float* btb = (const float*)d_in[15];
    const float* We1 = (const float*)d_in[16];
    const float* be1 = (const float*)d_in[17];
    const float* We0 = (const float*)d_in[18];
    const float* Wa1 = (const float*)d_in[19];
    const float* ba1 = (const float*)d_in[20];
    const float* Wa0 = (const float*)d_in[21];
    const float* W1 = (const float*)d_in[22];
    const float* b1 = (const float*)d_in[23];
    const float* W2 = (const float*)d_in[24];
    const float* b2 = (const float*)d_in[25];
    const float* W3 = (const float*)d_in[26];
    const float* b3 = (const float*)d_in[27];
    float* out = (float*)d_out;

    float* ws = (float*)d_ws;
    size_t off = 0;
    auto alloc = [&](size_t n) { float* p = ws + off; off += (n + 3) & ~(size_t)3; return p; };
    unsigned int* ePq = (unsigned int*)alloc((size_t)E * 64);   // e bf16, slot-major
    unsigned int* mPq = (unsigned int*)alloc((size_t)E * 64);   // m bf16, recv-sorted rows
    float* v_ = alloc((size_t)N * 128);
    unsigned int* vq = (unsigned int*)alloc((size_t)N * 64);    // v bf16-packed
    unsigned int* Gq = (unsigned int*)alloc((size_t)N * 64);    // gate bf16
    unsigned int* Pe1q = (unsigned int*)alloc((size_t)N * 64);
    unsigned int* Pe2q = (unsigned int*)alloc((size_t)N * 64);
    unsigned int* Pa1q = (unsigned int*)alloc((size_t)N * 64);
    unsigned int* Pa2q = (unsigned int*)alloc((size_t)N * 64);
    float* ef0 = alloc((size_t)E * 5);
    float* ang = alloc((size_t)A * 16);
    float* angS = alloc((size_t)A * 16);
    int* kat = (int*)alloc((size_t)A);
    int* katS = (int*)alloc((size_t)A);
    int* iij = (int*)alloc((size_t)A);
    int* cnt = (int*)alloc((size_t)E);
    int* start = (int*)alloc((size_t)E);
    int* fill = (int*)alloc((size_t)E);
    int* cntR = (int*)alloc((size_t)N);
    int* startR = (int*)alloc((size_t)N);
    int* fillR = (int*)alloc((size_t)N);
    int* epos = (int*)alloc((size_t)E);
    int* bsum = (int*)alloc(512);
    int* boff = (int*)alloc(256);
    int* acum = boff + 128;
    unsigned short* Bpk = (unsigned short*)alloc((size_t)32 * 8192);  // 32 mats bf16

    const int nscanE = (E + 2047) / 2048;
    const int nscanR = (N + 2047) / 2048;

    (void)hipMemsetAsync(cnt, 0, (size_t)E * 4, stream);
    (void)hipMemsetAsync(fill, 0, (size_t)E * 4, stream);
    (void)hipMemsetAsync(cntR, 0, (size_t)N * 4, stream);
    (void)hipMemsetAsync(fillR, 0, (size_t)N * 4, stream);
    k_offsets<<<1, 64, 0, stream>>>(tnb, tna, NG, boff, acum);
    k_angle_setup<<<(A + 255) / 256, 256, 0, stream>>>(tb, rnorm, cosang, ei, E, A, NG,
                                                       boff, acum, ang, kat, iij, cnt);
    k_scan1<<<nscanE, 256, 0, stream>>>(cnt, start, bsum, E);
    k_scan2<<<1, 256, 0, stream>>>(bsum, nscanE);
    k_scan3<<<(E + 255) / 256, 256, 0, stream>>>(start, bsum, E);
    k_scatter<<<(A + 255) / 256, 256, 0, stream>>>(ang, kat, iij, start, fill, angS, katS, A);
    k_hist_recv<<<(E + 255) / 256, 256, 0, stream>>>(ei, E, cntR);
    k_scan1<<<nscanR, 256, 0, stream>>>(cntR, startR, bsum, N);
    k_scan2<<<1, 256, 0, stream>>>(bsum, nscanR);
    k_scan3<<<(N + 255) / 256, 256, 0, stream>>>(startR, bsum, N);
    k_scatter_recv<<<(E + 255) / 256, 256, 0, stream>>>(ei, E, startR, fillR, epos);
    k_pack<<<256, 256, 0, stream>>>(Wg, Wtb, We1, Wa1, Bpk);
    k_edge_init<<<E / 16, 512, 0, stream>>>(dist, Wenc, benc, ePq, ef0);
    k_atom_init<<<(int)(((size_t)N * 64 + 255) / 256), 256, 0, stream>>>(an, emb, v_, vq, N);

    for (int b = 0; b < 4; ++b) {
        k_atom_pre<<<dim3(N / 64, 5), 256, 0, stream>>>(
            vq, Bpk + (size_t)(b * 8) * 16384, bg + b * 128,
            Gq, Pe1q, Pe2q, Pa1q, Pa2q);
        k_edge<<<E / 64, 256, 0, stream>>>(
            angS, katS, start, cnt, Gq, Wang + (size_t)b * 2048, ef0,
            ePq, ei, E, Pe1q, Pe2q, Pa1q, Pa2q, epos,
            Bpk + (size_t)(b * 8 + 5) * 16384,
            btb + b * 128, be1 + b * 128, We0 + (size_t)b * 640,
            ba1 + b * 128, Wa0 + (size_t)b * 640, mPq);
        k_dvagg<<<(N + 3) / 4, 256, 0, stream>>>(mPq, startR, cntR, v_, vq, N);
    }
    k_readout<<<N / 32, 256, 0, stream>>>(v_, W1, b1, W2, b2, W3, b3, out);
}

// Round 16
// 1111.227 us; speedup vs baseline: 1.1685x; 1.1685x over previous
//
#include <hip/hip_runtime.h>

// ---------------------------------------------------------------------------
// M3GNet forward. N=8000, E=200000, A=400000, NG=100, FD=128.
// R16 = R15 + GEMMs split into two nt-halves (acc[4] not acc[8], unroll 1 on
// the half loop) to push the GEMM-region VGPR peak under 128 -> 4 blocks/CU.
// (R12..R15 all plateau 1283-1298us at 3 blocks/CU; limiter is the register
// footprint in the GEMM region, not Phase 0.)
// ---------------------------------------------------------------------------

typedef short short8 __attribute__((ext_vector_type(8)));
typedef float f32x4v __attribute__((ext_vector_type(4)));

__device__ __forceinline__ float sigmoidf_(float x) { return 1.0f / (1.0f + __expf(-x)); }
__device__ __forceinline__ float swishf_(float x) { return x * sigmoidf_(x); }

__device__ __forceinline__ unsigned short f2bf(float x) {
    unsigned int u = __float_as_uint(x);
    unsigned int r = (u + 0x7FFFu + ((u >> 16) & 1u)) >> 16;
    return (unsigned short)r;
}
__device__ __forceinline__ float bf2f(unsigned short u) {
    return __uint_as_float(((unsigned int)u) << 16);
}
__device__ __forceinline__ float blo(unsigned int u) { return __uint_as_float(u << 16); }
__device__ __forceinline__ float bhi(unsigned int u) { return __uint_as_float(u & 0xffff0000u); }
__device__ __forceinline__ unsigned int pk2(float a, float b) {
    return (unsigned int)f2bf(a) | ((unsigned int)f2bf(b) << 16);
}
__device__ __forceinline__ unsigned int addbf2(unsigned int a, unsigned int b) {
    return pk2(blo(a) + blo(b), bhi(a) + bhi(b));
}

__device__ __forceinline__ f32x4v mfma_bf16(short8 a, short8 b, f32x4v c) {
    return __builtin_amdgcn_mfma_f32_16x16x32_bf16(a, b, c, 0, 0, 0);
}

__device__ __forceinline__ float4 f4add(float4 a, float4 b) {
    return make_float4(a.x + b.x, a.y + b.y, a.z + b.z, a.w + b.w);
}
__device__ __forceinline__ float4 f4swish(float4 a) {
    return make_float4(swishf_(a.x), swishf_(a.y), swishf_(a.z), swishf_(a.w));
}
__device__ __forceinline__ float getc(const float4& v, int i) {
    return i == 0 ? v.x : (i == 1 ? v.y : (i == 2 ? v.z : v.w));
}

#define FMA4(J, A) \
    acc[J].x = fmaf(A, bv.x, acc[J].x); acc[J].y = fmaf(A, bv.y, acc[J].y); \
    acc[J].z = fmaf(A, bv.z, acc[J].z); acc[J].w = fmaf(A, bv.w, acc[J].w)

template <int S>
__device__ __forceinline__ void gemm32f(const float* As, const float* __restrict__ B,
                                        int tm, int f0, float4 acc[4]) {
#pragma unroll 4
    for (int k = 0; k < 128; ++k) {
        const float4 a0 = *(const float4*)(As + k * S + (tm << 2));
        const float4 bv = *(const float4*)(B + (k << 7) + f0);
        FMA4(0, a0.x); FMA4(1, a0.y); FMA4(2, a0.z); FMA4(3, a0.w);
    }
}

// Phase-0 projection: m0/m1 = dot(ang16, Wang cols for this lane's 2 features)
#define ANG_PROJ(AP, M0, M1)                                                     \
    {                                                                            \
        const float4 A0 = (AP)[0], A1 = (AP)[1], A2 = (AP)[2], A3 = (AP)[3];     \
        float m0, m1;                                                            \
        m0 = A0.x * wc[0].x;  m1 = A0.x * wc[0].y;                               \
        m0 = fmaf(A0.y, wc[1].x, m0);  m1 = fmaf(A0.y, wc[1].y, m1);             \
        m0 = fmaf(A0.z, wc[2].x, m0);  m1 = fmaf(A0.z, wc[2].y, m1);             \
        m0 = fmaf(A0.w, wc[3].x, m0);  m1 = fmaf(A0.w, wc[3].y, m1);             \
        m0 = fmaf(A1.x, wc[4].x, m0);  m1 = fmaf(A1.x, wc[4].y, m1);             \
        m0 = fmaf(A1.y, wc[5].x, m0);  m1 = fmaf(A1.y, wc[5].y, m1);             \
        m0 = fmaf(A1.z, wc[6].x, m0);  m1 = fmaf(A1.z, wc[6].y, m1);             \
        m0 = fmaf(A1.w, wc[7].x, m0);  m1 = fmaf(A1.w, wc[7].y, m1);             \
        m0 = fmaf(A2.x, wc[8].x, m0);  m1 = fmaf(A2.x, wc[8].y, m1);             \
        m0 = fmaf(A2.y, wc[9].x, m0);  m1 = fmaf(A2.y, wc[9].y, m1);             \
        m0 = fmaf(A2.z, wc[10].x, m0); m1 = fmaf(A2.z, wc[10].y, m1);            \
        m0 = fmaf(A2.w, wc[11].x, m0); m1 = fmaf(A2.w, wc[11].y, m1);            \
        m0 = fmaf(A3.x, wc[12].x, m0); m1 = fmaf(A3.x, wc[12].y, m1);            \
        m0 = fmaf(A3.y, wc[13].x, m0); m1 = fmaf(A3.y, wc[13].y, m1);            \
        m0 = fmaf(A3.z, wc[14].x, m0); m1 = fmaf(A3.z, wc[14].y, m1);            \
        m0 = fmaf(A3.w, wc[15].x, m0); m1 = fmaf(A3.w, wc[15].y, m1);            \
        (M0) = m0; (M1) = m1;                                                    \
    }

// ---------------------------------------------------------------------------
__global__ void k_offsets(const int* __restrict__ tnb, const int* __restrict__ tna,
                          int NG, int* __restrict__ boff, int* __restrict__ acum) {
    if (threadIdx.x == 0 && blockIdx.x == 0) {
        int ab = 0, aa = 0;
        for (int g = 0; g < NG; ++g) {
            boff[g] = ab;
            ab += tnb[g];
            aa += tna[g];
            acum[g] = aa;
        }
    }
}

__global__ void k_angle_setup(const int* __restrict__ tb, const float* __restrict__ rnorm,
                              const float* __restrict__ cosang, const int* __restrict__ ei,
                              int E, int A, int NG,
                              const int* __restrict__ boff, const int* __restrict__ acum,
                              float* __restrict__ ang,
                              int* __restrict__ kat, int* __restrict__ iij,
                              int* __restrict__ cnt) {
    const int a = blockIdx.x * 256 + threadIdx.x;
    if (a >= A) return;
    int lo = 0, hi = NG - 1;
    while (lo < hi) {
        const int mid = (lo + hi) >> 1;
        if (a < acum[mid]) hi = mid; else lo = mid + 1;
    }
    const int off = boff[lo];
    iij[a] = tb[2 * a] + off;
    kat[a] = ei[(size_t)E + tb[2 * a + 1] + off];
    atomicAdd(&cnt[tb[2 * a] + off], 1);

    const float r = rnorm[a], c = cosang[a];
    const float rinv = 1.0f / r;
    const float x = r * 0.25f;
    const float fc = 1.0f + x * x * x * (-10.0f + x * (15.0f - 6.0f * x));
    const float fc2 = fc * fc;
    const float p2 = 1.5f * c * c - 0.5f;
    const float p3 = 2.5f * c * c * c - 1.5f * c;
    float4* ap = (float4*)(ang + (size_t)a * 16);
#pragma unroll
    for (int n = 0; n < 4; ++n) {
        const float rad = __sinf(r * (float)(n + 1) * 0.7853981633974483f) * rinv * fc2;
        ap[n] = make_float4(rad, rad * c, rad * p2, rad * p3);
    }
}

__global__ void k_scan1(const int* __restrict__ cnt, int* __restrict__ start,
                        int* __restrict__ bsum, int n) {
    __shared__ int sh[256];
    const int t = threadIdx.x;
    const int base = blockIdx.x * 2048 + t * 8;
    int v[8], s = 0;
#pragma unroll
    for (int i = 0; i < 8; ++i) { v[i] = (base + i < n) ? cnt[base + i] : 0; s += v[i]; }
    sh[t] = s;
    __syncthreads();
    for (int off = 1; off < 256; off <<= 1) {
        int x = (t >= off) ? sh[t - off] : 0;
        __syncthreads();
        sh[t] += x;
        __syncthreads();
    }
    if (t == 255) bsum[blockIdx.x] = sh[255];
    int run = sh[t] - s;
#pragma unroll
    for (int i = 0; i < 8; ++i) { if (base + i < n) start[base + i] = run; run += v[i]; }
}

__global__ void k_scan2(int* __restrict__ bsum, int nb) {
    __shared__ int sh[256];
    const int t = threadIdx.x;
    int v = (t < nb) ? bsum[t] : 0;
    sh[t] = v;
    __syncthreads();
    for (int off = 1; off < 256; off <<= 1) {
        int x = (t >= off) ? sh[t - off] : 0;
        __syncthreads();
        sh[t] += x;
        __syncthreads();
    }
    if (t < nb) bsum[t] = sh[t] - v;
}

__global__ void k_scan3(int* __restrict__ start, const int* __restrict__ bsum, int n) {
    const int i = blockIdx.x * 256 + threadIdx.x;
    if (i < n) start[i] += bsum[i >> 11];
}

__global__ void k_scatter(const float* __restrict__ ang,
                          const int* __restrict__ kat, const int* __restrict__ iij,
                          const int* __restrict__ start, int* __restrict__ fill,
                          float* __restrict__ angS, int* __restrict__ katS, int A) {
    const int a = blockIdx.x * 256 + threadIdx.x;
    if (a >= A) return;
    const int ij = iij[a];
    const int pos = start[ij] + atomicAdd(&fill[ij], 1);
    const float4* src = (const float4*)(ang + (size_t)a * 16);
    float4* dst = (float4*)(angS + (size_t)pos * 16);
#pragma unroll
    for (int j = 0; j < 4; ++j) dst[j] = src[j];
    katS[pos] = kat[a];
}

__global__ void k_hist_recv(const int* __restrict__ ei, int E, int* __restrict__ cntR) {
    const int e = blockIdx.x * 256 + threadIdx.x;
    if (e < E) atomicAdd(&cntR[ei[(size_t)E + e]], 1);
}

__global__ void k_scatter_recv(const int* __restrict__ ei, int E,
                               const int* __restrict__ startR, int* __restrict__ fillR,
                               int* __restrict__ epos) {
    const int e = blockIdx.x * 256 + threadIdx.x;
    if (e < E) {
        const int r = ei[(size_t)E + e];
        epos[e] = startR[r] + atomicAdd(&fillR[r], 1);
    }
}

// pack 32 weight matrices into MFMA B-frag layout (bf16).
// mat = b*8 + {0:Wg, 1:We1a, 2:We1b, 3:Wa1a, 4:Wa1b, 5:Wtb, 6:We1c, 7:Wa1c}
__global__ void k_pack(const float* __restrict__ Wg, const float* __restrict__ Wtb,
                       const float* __restrict__ We1, const float* __restrict__ Wa1,
                       unsigned short* __restrict__ Bpk) {
    const int gid = blockIdx.x * 256 + threadIdx.x;  // 0..65535
    const int mat = gid >> 11;
    const int t2 = gid & 2047;
    const int b = mat >> 3, which = mat & 7;
    const float* W;
    switch (which) {
        case 0: W = Wg + (size_t)b * 16384; break;
        case 1: W = We1 + (size_t)b * 49152; break;
        case 2: W = We1 + (size_t)b * 49152 + 16384; break;
        case 3: W = Wa1 + (size_t)b * 49152; break;
        case 4: W = Wa1 + (size_t)b * 49152 + 16384; break;
        case 5: W = Wtb + (size_t)b * 16384; break;
        case 6: W = We1 + (size_t)b * 49152 + 32768; break;
        default: W = Wa1 + (size_t)b * 49152 + 32768; break;
    }
    const int kc = t2 >> 9, nt = (t2 >> 6) & 7, lane = t2 & 63;
    const int q = lane >> 4, cc = lane & 15;
    const int col = nt * 16 + cc;
    union { unsigned short us[8]; uint4 v; } pk;
#pragma unroll
    for (int j = 0; j < 8; ++j)
        pk.us[j] = f2bf(W[(size_t)(kc * 32 + q * 8 + j) * 128 + col]);
    *(uint4*)(Bpk + (size_t)mat * 16384 + (size_t)((kc * 8 + nt) * 64 + lane) * 8) = pk.v;
}

// e init, slot-major layout: ePq[(strip*16 + s)*64 + lane], s = nt*2 + half.
__global__ void k_edge_init(const float* __restrict__ dist, const float* __restrict__ Wenc,
                            const float* __restrict__ benc, unsigned int* __restrict__ ePq,
                            float* __restrict__ ef0) {
    __shared__ float sarr[16][5];
    const int s = blockIdx.x, t = threadIdx.x;
    if (t < 16) {
        const float r = dist[s * 16 + t];
        const float rinv = 1.0f / r;
#pragma unroll
        for (int n = 0; n < 5; ++n) {
            const float v = 0.6324555320336759f * __sinf(r * (float)(n + 1) * 0.6283185307179586f) * rinv;
            sarr[t][n] = v;
            ef0[(size_t)(s * 16 + t) * 5 + n] = v;
        }
    }
    __syncthreads();
    const int lane = t >> 3, nt = t & 7;
    const int q = lane >> 4;
    const int f = nt * 16 + (lane & 15);
    float wv[5];
#pragma unroll
    for (int n = 0; n < 5; ++n) wv[n] = Wenc[n * 128 + f];
    const float bz = benc[f];
    float o[4];
#pragma unroll
    for (int r = 0; r < 4; ++r) {
        const int m = q * 4 + r;
        float acc = bz;
#pragma unroll
        for (int n = 0; n < 5; ++n) acc = fmaf(sarr[m][n], wv[n], acc);
        o[r] = swishf_(acc);
    }
    unsigned int* epB = ePq + (size_t)s * 1024;
    epB[(nt * 2) * 64 + lane] = pk2(o[0], o[1]);
    epB[(nt * 2 + 1) * 64 + lane] = pk2(o[2], o[3]);
}

// atom init: v fp32 + vq bf16-packed (lane j holds features 2j,2j+1)
__global__ void k_atom_init(const int* __restrict__ an, const float* __restrict__ emb,
                            float* __restrict__ v, unsigned int* __restrict__ vq, int N) {
    const size_t gid = (size_t)blockIdx.x * 256 + threadIdx.x;
    if (gid >= (size_t)N * 64) return;
    const int a = (int)(gid >> 6), j = (int)(gid & 63);
    const float2 e = *(const float2*)(emb + (size_t)an[a] * 128 + 2 * j);
    *(float2*)(v + (size_t)a * 128 + 2 * j) = e;
    vq[gid] = pk2(e.x, e.y);
}

// ---------------------------------------------------------------------------
// MFMA per-atom GEMMs: 64 atoms/block, wave w owns atoms 16w..16w+15.
__global__ void __launch_bounds__(256, 4) k_atom_pre(
    const unsigned int* __restrict__ vq,
    const unsigned short* __restrict__ Bpk5, const float* __restrict__ bg,
    unsigned int* __restrict__ Gq, unsigned int* __restrict__ Pe1q,
    unsigned int* __restrict__ Pe2q,
    unsigned int* __restrict__ Pa1q, unsigned int* __restrict__ Pa2q) {
    __shared__ __align__(16) unsigned short At[64 * 136];
    unsigned int* At32 = (unsigned int*)At;
    const int t = threadIdx.x;
    const int w = t >> 6, l = t & 63;
    const int q = l >> 4, c = l & 15;
    const int g = blockIdx.y;
    const int abase = blockIdx.x * 64 + 16 * w;

    const unsigned short* vh = (const unsigned short*)vq;
    short8 af[4];
#pragma unroll
    for (int kc = 0; kc < 4; ++kc)
        af[kc] = *(const short8*)(vh + (size_t)(abase + c) * 128 + kc * 32 + q * 8);

    const short8* Bp = (const short8*)(Bpk5 + (size_t)g * 16384);
    const f32x4v zz = {0.0f, 0.0f, 0.0f, 0.0f};
    f32x4v acc[8];
#pragma unroll
    for (int nt = 0; nt < 8; ++nt) acc[nt] = zz;
#pragma unroll
    for (int nt = 0; nt < 8; ++nt)
#pragma unroll
        for (int kc = 0; kc < 4; ++kc)
            acc[nt] = mfma_bf16(af[kc], Bp[(kc * 8 + nt) * 64 + l], acc[nt]);

    unsigned int* OUT = (g == 0) ? Gq : (g == 1) ? Pe1q : (g == 2) ? Pe2q
                      : (g == 3) ? Pa1q : Pa2q;
#pragma unroll
    for (int nt = 0; nt < 8; ++nt) {
        const int fo = nt * 16 + c;
        if (g == 0) {
            const float bz = bg[fo];
#pragma unroll
            for (int r = 0; r < 4; ++r)
                At[(16 * w + q * 4 + r) * 136 + fo] = f2bf(sigmoidf_(acc[nt][r] + bz));
        } else {
#pragma unroll
            for (int r = 0; r < 4; ++r)
                At[(16 * w + q * 4 + r) * 136 + fo] = f2bf(acc[nt][r]);
        }
    }
#pragma unroll
    for (int j = 0; j < 16; ++j)
        OUT[(size_t)(abase + j) * 64 + l] = At32[(16 * w + j) * 68 + l];
}

// ---------------------------------------------------------------------------
// Fused per-edge kernel: Phase 0 (flat CSR loop) + 3 MFMA GEMMs, each GEMM
// computed in two nt-halves (acc[4]) to cut the register peak.
__global__ void __launch_bounds__(256, 4) k_edge(
    const float* __restrict__ angS, const int* __restrict__ katS,
    const int* __restrict__ startA, const int* __restrict__ cntA,
    const unsigned int* __restrict__ Gq, const float* __restrict__ Wang,
    const float* __restrict__ ef0g,
    unsigned int* __restrict__ ePq, const int* __restrict__ ei, int E,
    const unsigned int* __restrict__ Pe1q, const unsigned int* __restrict__ Pe2q,
    const unsigned int* __restrict__ Pa1q, const unsigned int* __restrict__ Pa2q,
    const int* __restrict__ epos,
    const unsigned short* __restrict__ Bpk3,
    const float* __restrict__ btb, const float* __restrict__ be1,
    const float* __restrict__ We0, const float* __restrict__ ba1,
    const float* __restrict__ Wa0, unsigned int* __restrict__ mPq) {
    __shared__ __align__(16) unsigned short At[64 * 136];
    __shared__ __align__(16) unsigned short sPh[64 * 136];
    __shared__ float sef0[320];
    __shared__ int sA0[64], sAn[64];
    unsigned int* At32 = (unsigned int*)At;
    unsigned int* sP32 = (unsigned int*)sPh;

    const int t = threadIdx.x;
    const int w = t >> 6, l = t & 63;
    const int q = l >> 4, c = l & 15;
    const int g4 = l >> 4, l16 = l & 15;
    const size_t base = (size_t)blockIdx.x * 64;
    const int wbase = (int)base + 16 * w;

    for (int i = t; i < 320; i += 256) sef0[i] = ef0g[base * 5 + i];
    if (l < 16) {
        sA0[16 * w + l] = startA[wbase + l];
        sAn[16 * w + l] = cntA[wbase + l];
    }

#define STAGE_SP(P1, P2)                                                         \
    _Pragma("unroll") for (int i = 0; i < 4; ++i) {                              \
        const int j = i * 4 + g4;                                                \
        const int es_ = ei[wbase + j];                                           \
        const int rc_ = ei[(size_t)E + wbase + j];                               \
        const uint4 u1 = *(const uint4*)((P1) + (size_t)es_ * 64 + l16 * 4);     \
        const uint4 u2 = *(const uint4*)((P2) + (size_t)rc_ * 64 + l16 * 4);     \
        uint4 o;                                                                 \
        o.x = addbf2(u1.x, u2.x); o.y = addbf2(u1.y, u2.y);                      \
        o.z = addbf2(u1.z, u2.z); o.w = addbf2(u1.w, u2.w);                      \
        *(uint4*)(sP32 + (16 * w + j) * 68 + l16 * 4) = o;                       \
    }

    // stage Pe sums into LDS ahead of Phase 0 (consumed after the barrier)
    STAGE_SP(Pe1q, Pe2q)
    unsigned int* epB = ePq + (size_t)(blockIdx.x * 4 + w) * 1024;  // slot-major

    // ---- Phase 0: flat loop over this wave's contiguous angle range.
    {
        float2 wc[16];
#pragma unroll
        for (int k = 0; k < 16; ++k) wc[k] = *(const float2*)(Wang + k * 128 + 2 * l);

        int j = 0;
        const int aBeg = __builtin_amdgcn_readfirstlane(sA0[16 * w]);
        const int aEnd = __builtin_amdgcn_readfirstlane(sA0[16 * w + 15] + sAn[16 * w + 15]);
        int nextB = __builtin_amdgcn_readfirstlane(sA0[16 * w] + sAn[16 * w]);
        float aa0 = 0.0f, aa1 = 0.0f;

#define FLUSH_TO(AIDX)                                                           \
        while ((AIDX) >= nextB && j < 15) {                                      \
            At32[(16 * w + j) * 68 + l] = pk2(aa0, aa1);                         \
            aa0 = 0.0f; aa1 = 0.0f;                                              \
            ++j;                                                                 \
            nextB = __builtin_amdgcn_readfirstlane(sA0[16 * w + j] + sAn[16 * w + j]); \
        }

        int a = aBeg;
        for (; a + 1 < aEnd; a += 2) {
            const int ka0 = __builtin_amdgcn_readfirstlane(katS[a]);
            const int ka1 = __builtin_amdgcn_readfirstlane(katS[a + 1]);
            const unsigned int gv0 = Gq[(size_t)ka0 * 64 + l];
            const unsigned int gv1 = Gq[(size_t)ka1 * 64 + l];
            const float4* ap0 = (const float4*)(angS + (size_t)a * 16);
            const float4* ap1 = (const float4*)(angS + (size_t)(a + 1) * 16);
            float m0a, m1a, m0b, m1b;
            ANG_PROJ(ap0, m0a, m1a)
            ANG_PROJ(ap1, m0b, m1b)
            FLUSH_TO(a)
            aa0 = fmaf(m0a, blo(gv0), aa0);
            aa1 = fmaf(m1a, bhi(gv0), aa1);
            FLUSH_TO(a + 1)
            aa0 = fmaf(m0b, blo(gv1), aa0);
            aa1 = fmaf(m1b, bhi(gv1), aa1);
        }
        if (a < aEnd) {
            const int ka0 = __builtin_amdgcn_readfirstlane(katS[a]);
            const unsigned int gv0 = Gq[(size_t)ka0 * 64 + l];
            const float4* ap0 = (const float4*)(angS + (size_t)a * 16);
            float m0a, m1a;
            ANG_PROJ(ap0, m0a, m1a)
            FLUSH_TO(a)
            aa0 = fmaf(m0a, blo(gv0), aa0);
            aa1 = fmaf(m1a, bhi(gv0), aa1);
        }
        At32[(16 * w + j) * 68 + l] = pk2(aa0, aa1);
        for (int jj = j + 1; jj < 16; ++jj) At32[(16 * w + jj) * 68 + l] = 0u;
#undef FLUSH_TO
    }
    __syncthreads();   // the only cross-wave barrier

    const short8* Bp1 = (const short8*)Bpk3;
    const short8* Bp2 = Bp1 + 2048;
    const short8* Bp3 = Bp2 + 2048;
    const f32x4v zz = {0.0f, 0.0f, 0.0f, 0.0f};

    short8 af[4];
#define LOAD_AF                                                                  \
    _Pragma("unroll") for (int kc = 0; kc < 4; ++kc)                             \
        af[kc] = *(const short8*)(At + (16 * w + c) * 136 + kc * 32 + q * 8);
// transpose from packed er2: row=edge (q*4+r), col=feature (nt*16+c)
#define TRANSPOSE_ER2                                                            \
    _Pragma("unroll") for (int nt = 0; nt < 8; ++nt) {                           \
        At[(16 * w + q * 4 + 0) * 136 + nt * 16 + c] = (unsigned short)er2[2 * nt];        \
        At[(16 * w + q * 4 + 1) * 136 + nt * 16 + c] = (unsigned short)(er2[2 * nt] >> 16);\
        At[(16 * w + q * 4 + 2) * 136 + nt * 16 + c] = (unsigned short)er2[2 * nt + 1];    \
        At[(16 * w + q * 4 + 3) * 136 + nt * 16 + c] = (unsigned short)(er2[2 * nt + 1] >> 16);\
    }

    unsigned int er2[16];

    // ---- GEMM1: agg @ Wtb; e += swish(. + btb)  (two nt-halves, acc[4])
    LOAD_AF
#pragma unroll 1
    for (int h = 0; h < 2; ++h) {
        f32x4v acc[4];
#pragma unroll
        for (int n2 = 0; n2 < 4; ++n2) acc[n2] = zz;
#pragma unroll
        for (int n2 = 0; n2 < 4; ++n2)
#pragma unroll
            for (int kc = 0; kc < 4; ++kc)
                acc[n2] = mfma_bf16(af[kc], Bp1[(kc * 8 + h * 4 + n2) * 64 + l], acc[n2]);
#pragma unroll
        for (int n2 = 0; n2 < 4; ++n2) {
            const int nt = h * 4 + n2;
            const unsigned int e0 = epB[(2 * nt) * 64 + l];       // coalesced
            const unsigned int e1 = epB[(2 * nt + 1) * 64 + l];
            const float bt = btb[nt * 16 + c];
            er2[2 * nt] = pk2(blo(e0) + swishf_(acc[n2][0] + bt),
                              bhi(e0) + swishf_(acc[n2][1] + bt));
            er2[2 * nt + 1] = pk2(blo(e1) + swishf_(acc[n2][2] + bt),
                                  bhi(e1) + swishf_(acc[n2][3] + bt));
        }
    }
    TRANSPOSE_ER2   // wave-private slab: no barrier needed

    float efs[4][5];
#pragma unroll
    for (int r = 0; r < 4; ++r)
#pragma unroll
        for (int n = 0; n < 5; ++n) efs[r][n] = sef0[(16 * w + q * 4 + r) * 5 + n];

    // ---- GEMM2: e @ We1[256:384]; e += swish(. + be1 + Psum) * (ef0@We0)
    LOAD_AF
#pragma unroll 1
    for (int h = 0; h < 2; ++h) {
        f32x4v acc[4];
#pragma unroll
        for (int n2 = 0; n2 < 4; ++n2) acc[n2] = zz;
#pragma unroll
        for (int n2 = 0; n2 < 4; ++n2)
#pragma unroll
            for (int kc = 0; kc < 4; ++kc)
                acc[n2] = mfma_bf16(af[kc], Bp2[(kc * 8 + h * 4 + n2) * 64 + l], acc[n2]);
#pragma unroll
        for (int n2 = 0; n2 < 4; ++n2) {
            const int nt = h * 4 + n2;
            const int fo = nt * 16 + c;
            const float bt = be1[fo];
            const float w0 = We0[fo], w1 = We0[128 + fo], w2 = We0[256 + fo],
                        w3 = We0[384 + fo], w4 = We0[512 + fo];
            float vv[4];
#pragma unroll
            for (int r = 0; r < 4; ++r) {
                const float p12 = bf2f(sPh[(16 * w + q * 4 + r) * 136 + fo]);
                const float x = acc[n2][r] + bt + p12;
                float sc = efs[r][0] * w0;
                sc = fmaf(efs[r][1], w1, sc);
                sc = fmaf(efs[r][2], w2, sc);
                sc = fmaf(efs[r][3], w3, sc);
                sc = fmaf(efs[r][4], w4, sc);
                const unsigned int eold = er2[2 * nt + (r >> 1)];
                const float eb = (r & 1) ? bhi(eold) : blo(eold);
                vv[r] = eb + swishf_(x) * sc;
            }
            er2[2 * nt] = pk2(vv[0], vv[1]);
            er2[2 * nt + 1] = pk2(vv[2], vv[3]);
            epB[(2 * nt) * 64 + l] = er2[2 * nt];          // coalesced
            epB[(2 * nt + 1) * 64 + l] = er2[2 * nt + 1];  // coalesced
        }
    }
    STAGE_SP(Pa1q, Pa2q)
    TRANSPOSE_ER2

    // ---- GEMM3: e @ Wa1[256:384]; m -> At (bf16) -> mPq at recv-sorted slots
    LOAD_AF
#pragma unroll 1
    for (int h = 0; h < 2; ++h) {
        f32x4v acc[4];
#pragma unroll
        for (int n2 = 0; n2 < 4; ++n2) acc[n2] = zz;
#pragma unroll
        for (int n2 = 0; n2 < 4; ++n2)
#pragma unroll
            for (int kc = 0; kc < 4; ++kc)
                acc[n2] = mfma_bf16(af[kc], Bp3[(kc * 8 + h * 4 + n2) * 64 + l], acc[n2]);
#pragma unroll
        for (int n2 = 0; n2 < 4; ++n2) {
            const int nt = h * 4 + n2;
            const int fo = nt * 16 + c;
            const float bt = ba1[fo];
            const float w0 = Wa0[fo], w1 = Wa0[128 + fo], w2 = Wa0[256 + fo],
                        w3 = Wa0[384 + fo], w4 = Wa0[512 + fo];
#pragma unroll
            for (int r = 0; r < 4; ++r) {
                const float p12 = bf2f(sPh[(16 * w + q * 4 + r) * 136 + fo]);
                const float x = acc[n2][r] + bt + p12;
                float sc = efs[r][0] * w0;
                sc = fmaf(efs[r][1], w1, sc);
                sc = fmaf(efs[r][2], w2, sc);
                sc = fmaf(efs[r][3], w3, sc);
                sc = fmaf(efs[r][4], w4, sc);
                At[(16 * w + q * 4 + r) * 136 + fo] = f2bf(swishf_(x) * sc);
            }
        }
    }
#pragma unroll
    for (int j = 0; j < 16; ++j) {
        const int ep = epos[wbase + j];
        mPq[(size_t)ep * 64 + l] = At32[(16 * w + j) * 68 + l];  // 256B full-line row
    }
#undef LOAD_AF
#undef TRANSPOSE_ER2
#undef STAGE_SP
}

// dv aggregation (streaming reads: mPq is recv-sorted) fused with v update + vq
__global__ void k_dvagg(const unsigned int* __restrict__ mPq,
                        const int* __restrict__ startR, const int* __restrict__ cntR,
                        float* __restrict__ v, unsigned int* __restrict__ vq, int N) {
    const int a = blockIdx.x * 4 + (threadIdx.x >> 6);
    if (a >= N) return;
    const int l = threadIdx.x & 63;
    const int s0 = startR[a], n = cntR[a];
    float a0 = 0.0f, a1 = 0.0f;
    for (int i = 0; i < n; ++i) {
        const unsigned int u = mPq[(size_t)(s0 + i) * 64 + l];
        a0 += blo(u);
        a1 += bhi(u);
    }
    const float v0 = v[(size_t)a * 128 + 2 * l] + a0;
    const float v1 = v[(size_t)a * 128 + 2 * l + 1] + a1;
    v[(size_t)a * 128 + 2 * l] = v0;
    v[(size_t)a * 128 + 2 * l + 1] = v1;
    vq[(size_t)a * 64 + l] = pk2(v0, v1);
}

__global__ void k_readout(const float* __restrict__ v,
                          const float* __restrict__ W1, const float* __restrict__ b1,
                          const float* __restrict__ W2, const float* __restrict__ b2,
                          const float* __restrict__ W3, const float* __restrict__ b3,
                          float* __restrict__ out) {
    __shared__ float At[128 * 36];
    const int t = threadIdx.x;
    const int tn = t & 31, tm = t >> 5;
    const int f0 = tn << 2;
    const size_t base = (size_t)blockIdx.x * 32;
    {
        const int m = t & 31, cb = t >> 5;
        const float4* src = (const float4*)(v + (base + m) * 128);
#pragma unroll
        for (int i = 0; i < 4; ++i) {
            const int c = cb + (i << 3);
            const float4 ld = src[c];
            float* dst = At + (c << 2) * 32 + m;
            dst[0] = ld.x; dst[32] = ld.y; dst[64] = ld.z; dst[96] = ld.w;
        }
    }
    __syncthreads();
    float4 acc[4] = {};
    gemm32f<32>(At, W1, tm, f0, acc);
    {
        const float4 bv1 = *(const float4*)(b1 + f0);
#pragma unroll
        for (int j = 0; j < 4; ++j) acc[j] = f4swish(f4add(acc[j], bv1));
    }
    __syncthreads();
#pragma unroll
    for (int i = 0; i < 4; ++i) {
        float4 w0;
        w0.x = getc(acc[0], i); w0.y = getc(acc[1], i); w0.z = getc(acc[2], i); w0.w = getc(acc[3], i);
        *(float4*)(At + (f0 + i) * 36 + (tm << 2)) = w0;
    }
    __syncthreads();
    float4 acc2[4] = {};
    gemm32f<36>(At, W2, tm, f0, acc2);
    const float4 bv2 = *(const float4*)(b2 + f0);
    const float4 w3v = *(const float4*)(W3 + f0);
#pragma unroll
    for (int j = 0; j < 4; ++j) {
        const float4 h = f4swish(f4add(acc2[j], bv2));
        float p = h.x * w3v.x + h.y * w3v.y + h.z * w3v.z + h.w * w3v.w;
        p += __shfl_xor(p, 16);
        p += __shfl_xor(p, 8);
        p += __shfl_xor(p, 4);
        p += __shfl_xor(p, 2);
        p += __shfl_xor(p, 1);
        if (tn == 0) out[base + (tm << 2) + j] = p + b3[0];
    }
}

// ---------------------------------------------------------------------------
extern "C" void kernel_launch(void* const* d_in, const int* in_sizes, int n_in,
                              void* d_out, int out_size, void* d_ws, size_t ws_size,
                              hipStream_t stream) {
    const int N = in_sizes[0];
    const int E = in_sizes[2];
    const int A = in_sizes[4];
    const int NG = in_sizes[6];

    const int* an = (const int*)d_in[0];
    const int* ei = (const int*)d_in[1];
    const float* dist = (const float*)d_in[2];
    const int* tb = (const int*)d_in[3];
    const float* rnorm = (const float*)d_in[4];
    const float* cosang = (const float*)d_in[5];
    const int* tnb = (const int*)d_in[6];
    const int* tna = (const int*)d_in[7];
    const float* emb = (const float*)d_in[8];
    const float* Wenc = (const float*)d_in[9];
    const float* benc = (const float*)d_in[10];
    const float* Wang = (const float*)d_in[11];
    const float* Wg = (const float*)d_in[12];
    const float* bg = (const float*)d_in[13];
    const float* Wtb = (const float*)d_in[14];
    const float* btb = (const float*)d_in[15];
    const float* We1 = (const float*)d_in[16];
    const float* be1 = (const float*)d_in[17];
    const float* We0 = (const float*)d_in[18];
    const float* Wa1 = (const float*)d_in[19];
    const float* ba1 = (const float*)d_in[20];
    const float* Wa0 = (const float*)d_in[21];
    const float* W1 = (const float*)d_in[22];
    const float* b1 = (const float*)d_in[23];
    const float* W2 = (const float*)d_in[24];
    const float* b2 = (const float*)d_in[25];
    const float* W3 = (const float*)d_in[26];
    const float* b3 = (const float*)d_in[27];
    float* out = (float*)d_out;

    float* ws = (float*)d_ws;
    size_t off = 0;
    auto alloc = [&](size_t n) { float* p = ws + off; off += (n + 3) & ~(size_t)3; return p; };
    unsigned int* ePq = (unsigned int*)alloc((size_t)E * 64);   // e bf16, slot-major
    unsigned int* mPq = (unsigned int*)alloc((size_t)E * 64);   // m bf16, recv-sorted rows
    float* v_ = alloc((size_t)N * 128);
    unsigned int* vq = (unsigned int*)alloc((size_t)N * 64);    // v bf16-packed
    unsigned int* Gq = (unsigned int*)alloc((size_t)N * 64);    // gate bf16
    unsigned int* Pe1q = (unsigned int*)alloc((size_t)N * 64);
    unsigned int* Pe2q = (unsigned int*)alloc((size_t)N * 64);
    unsigned int* Pa1q = (unsigned int*)alloc((size_t)N * 64);
    unsigned int* Pa2q = (unsigned int*)alloc((size_t)N * 64);
    float* ef0 = alloc((size_t)E * 5);
    float* ang = alloc((size_t)A * 16);
    float* angS = alloc((size_t)A * 16);
    int* kat = (int*)alloc((size_t)A);
    int* katS = (int*)alloc((size_t)A);
    int* iij = (int*)alloc((size_t)A);
    int* cnt = (int*)alloc((size_t)E);
    int* start = (int*)alloc((size_t)E);
    int* fill = (int*)alloc((size_t)E);
    int* cntR = (int*)alloc((size_t)N);
    int* startR = (int*)alloc((size_t)N);
    int* fillR = (int*)alloc((size_t)N);
    int* epos = (int*)alloc((size_t)E);
    int* bsum = (int*)alloc(512);
    int* boff = (int*)alloc(256);
    int* acum = boff + 128;
    unsigned short* Bpk = (unsigned short*)alloc((size_t)32 * 8192);  // 32 mats bf16

    const int nscanE = (E + 2047) / 2048;
    const int nscanR = (N + 2047) / 2048;

    (void)hipMemsetAsync(cnt, 0, (size_t)E * 4, stream);
    (void)hipMemsetAsync(fill, 0, (size_t)E * 4, stream);
    (void)hipMemsetAsync(cntR, 0, (size_t)N * 4, stream);
    (void)hipMemsetAsync(fillR, 0, (size_t)N * 4, stream);
    k_offsets<<<1, 64, 0, stream>>>(tnb, tna, NG, boff, acum);
    k_angle_setup<<<(A + 255) / 256, 256, 0, stream>>>(tb, rnorm, cosang, ei, E, A, NG,
                                                       boff, acum, ang, kat, iij, cnt);
    k_scan1<<<nscanE, 256, 0, stream>>>(cnt, start, bsum, E);
    k_scan2<<<1, 256, 0, stream>>>(bsum, nscanE);
    k_scan3<<<(E + 255) / 256, 256, 0, stream>>>(start, bsum, E);
    k_scatter<<<(A + 255) / 256, 256, 0, stream>>>(ang, kat, iij, start, fill, angS, katS, A);
    k_hist_recv<<<(E + 255) / 256, 256, 0, stream>>>(ei, E, cntR);
    k_scan1<<<nscanR, 256, 0, stream>>>(cntR, startR, bsum, N);
    k_scan2<<<1, 256, 0, stream>>>(bsum, nscanR);
    k_scan3<<<(N + 255) / 256, 256, 0, stream>>>(startR, bsum, N);
    k_scatter_recv<<<(E + 255) / 256, 256, 0, stream>>>(ei, E, startR, fillR, epos);
    k_pack<<<256, 256, 0, stream>>>(Wg, Wtb, We1, Wa1, Bpk);
    k_edge_init<<<E / 16, 512, 0, stream>>>(dist, Wenc, benc, ePq, ef0);
    k_atom_init<<<(int)(((size_t)N * 64 + 255) / 256), 256, 0, stream>>>(an, emb, v_, vq, N);

    for (int b = 0; b < 4; ++b) {
        k_atom_pre<<<dim3(N / 64, 5), 256, 0, stream>>>(
            vq, Bpk + (size_t)(b * 8) * 16384, bg + b * 128,
            Gq, Pe1q, Pe2q, Pa1q, Pa2q);
        k_edge<<<E / 64, 256, 0, stream>>>(
            angS, katS, start, cnt, Gq, Wang + (size_t)b * 2048, ef0,
            ePq, ei, E, Pe1q, Pe2q, Pa1q, Pa2q, epos,
            Bpk + (size_t)(b * 8 + 5) * 16384,
            btb + b * 128, be1 + b * 128, We0 + (size_t)b * 640,
            ba1 + b * 128, Wa0 + (size_t)b * 640, mPq);
        k_dvagg<<<(N + 3) / 4, 256, 0, stream>>>(mPq, startR, cntR, v_, vq, N);
    }
    k_readout<<<N / 32, 256, 0, stream>>>(v_, W1, b1, W2, b2, W3, b3, out);
}